// Round 3
// baseline (183.660 us; speedup 1.0000x reference)
//
#include <hip/hip_runtime.h>

#define HW    3136   // 56*56
#define KK    196
#define BCN   256    // B*C
#define KT    7      // k's per main block
#define NKC   28     // KK / KT
#define NSEG  49     // hw segments of 64
#define LOG2E 1.4426950408889634f

// ---- Kernel 1: transpose+scale u[bc][hw] -> uT2[hw/2][bc] (hw-pairs), and zero tickets.
__global__ __launch_bounds__(256) void rf_prep(const float* __restrict__ u,
                                               float2* __restrict__ uT2,
                                               unsigned* __restrict__ cnt) {
    if (blockIdx.x == 0 && blockIdx.y == 0 && threadIdx.x < NKC)
        cnt[threadIdx.x] = 0u;
    __shared__ float tile[16][65];
    const int t  = threadIdx.x;
    const int h0 = blockIdx.x * 64;   // 49 hw tiles
    const int b0 = blockIdx.y * 16;   // 16 bc tiles
    const int c  = t & 63;
    const int r  = t >> 6;            // 0..3
    #pragma unroll
    for (int j = 0; j < 4; ++j)
        tile[r + 4*j][c] = u[(b0 + r + 4*j) * HW + h0 + c] * LOG2E;
    __syncthreads();
    const int tw  = t & 15;           // bc within tile
    const int hp0 = t >> 4;           // 0..15
    #pragma unroll
    for (int i = 0; i < 2; ++i) {
        const int hp = hp0 + 16 * i;  // 0..31
        float2 v;
        v.x = tile[tw][2*hp];
        v.y = tile[tw][2*hp + 1];
        uT2[(size_t)(h0/2 + hp) * BCN + b0 + tw] = v;
    }
}

// ---- Kernel 2: main + fused finalize. grid (49 seg, 28 kc), block 256 (lane = bc).
__global__ __launch_bounds__(256) void rf_main(const float2* __restrict__ uT2,
                                               const float* __restrict__ rfs,
                                               float* __restrict__ part,
                                               unsigned* __restrict__ cnt,
                                               float* __restrict__ out) {
    const int seg = blockIdx.x;            // 0..48
    const int kc  = blockIdx.y;            // 0..27
    const int t   = threadIdx.x;           // bc
    const int k0  = kc * KT;
    const int h0  = seg * 64;

    float acc[KT][2];
    #pragma unroll
    for (int j = 0; j < KT; ++j) { acc[j][0] = 0.f; acc[j][1] = 0.f; }

    const float2* up = uT2 + (size_t)(h0/2) * BCN + t;
    const float*  rp = rfs + (size_t)h0 * KK + k0;   // wave-uniform
    #pragma unroll 4
    for (int hp = 0; hp < 32; ++hp) {
        const float2 uv = up[(size_t)hp * BCN];
        #pragma unroll
        for (int j = 0; j < KT; ++j) {
            const float r0 = rp[(2*hp)     * KK + j];
            const float r1 = rp[(2*hp + 1) * KK + j];
            acc[j][0] += __builtin_amdgcn_exp2f(uv.x * r0);
            acc[j][1] += __builtin_amdgcn_exp2f(uv.y * r1);
        }
    }

    float* pp = part + (size_t)(kc * NSEG + seg) * KT * BCN + t;
    #pragma unroll
    for (int j = 0; j < KT; ++j)
        pp[j * BCN] = acc[j][0] + acc[j][1];

    // ---- ticket: last block of this kc column reduces and writes out.
    __threadfence();                       // release partial stores (device scope)
    __shared__ int lastflag;
    if (t == 0) {
        const unsigned old = atomicAdd(&cnt[kc], 1u);
        lastflag = (old == NSEG - 1) ? 1 : 0;
    }
    __syncthreads();
    if (lastflag) {
        __threadfence();                   // acquire other blocks' partials
        const float* pb = part + (size_t)kc * NSEG * KT * BCN + t;
        float s[KT];
        #pragma unroll
        for (int j = 0; j < KT; ++j) s[j] = 0.f;
        for (int sg = 0; sg < NSEG; ++sg) {
            #pragma unroll
            for (int j = 0; j < KT; ++j)
                s[j] += pb[(sg * KT + j) * BCN];
        }
        #pragma unroll
        for (int j = 0; j < KT; ++j) {
            const float v = s[j];
            out[(size_t)t * KK + k0 + j] = v / (1.0f + v);
        }
    }
}

// ---- Fallback (no workspace): monolithic, lane = k. Known-correct path.
__global__ __launch_bounds__(256) void rf_pool_fallback(const float* __restrict__ u,
                                                        const float* __restrict__ rfs,
                                                        float* __restrict__ out) {
    const int grp = blockIdx.x;
    const int tid = threadIdx.x;
    const int bc0 = grp * 8;
    __shared__ __align__(16) float u_lds[8][196];
    float sum[8];
    #pragma unroll
    for (int g = 0; g < 8; ++g) sum[g] = 0.0f;
    for (int base = 0; base < HW; base += 196) {
        __syncthreads();
        if (tid < 196) {
            #pragma unroll
            for (int g = 0; g < 8; ++g)
                u_lds[g][tid] = u[(bc0 + g) * HW + base + tid] * LOG2E;
        }
        __syncthreads();
        if (tid < KK) {
            const float* rp = rfs + (size_t)base * KK + tid;
            for (int h = 0; h < 196; h += 4) {
                float rf0 = rp[(h + 0) * KK];
                float rf1 = rp[(h + 1) * KK];
                float rf2 = rp[(h + 2) * KK];
                float rf3 = rp[(h + 3) * KK];
                #pragma unroll
                for (int g = 0; g < 8; ++g) {
                    float4 ug = *(const float4*)&u_lds[g][h];
                    sum[g] += __builtin_amdgcn_exp2f(ug.x * rf0);
                    sum[g] += __builtin_amdgcn_exp2f(ug.y * rf1);
                    sum[g] += __builtin_amdgcn_exp2f(ug.z * rf2);
                    sum[g] += __builtin_amdgcn_exp2f(ug.w * rf3);
                }
            }
        }
    }
    if (tid < KK) {
        #pragma unroll
        for (int g = 0; g < 8; ++g) {
            float s = sum[g];
            out[(bc0 + g) * KK + tid] = s / (s + 1.0f);
        }
    }
}

extern "C" void kernel_launch(void* const* d_in, const int* in_sizes, int n_in,
                              void* d_out, int out_size, void* d_ws, size_t ws_size,
                              hipStream_t stream) {
    const float* u   = (const float*)d_in[0];   // (8,32,56,56) f32
    const float* rfs = (const float*)d_in[1];   // (56,56,196) f32
    float* out = (float*)d_out;                 // (8,32,196) f32

    const size_t uT2_off  = 0;                                   // 3.2 MB
    const size_t part_off = 4u << 20;                            // @4 MB, 9.84 MB
    const size_t cnt_off  = part_off + (15u << 20);              // @19 MB
    const size_t need     = cnt_off + 4096;
    if (ws_size >= need) {
        float2*   uT2  = (float2*)((char*)d_ws + uT2_off);
        float*    part = (float*)((char*)d_ws + part_off);
        unsigned* cnt  = (unsigned*)((char*)d_ws + cnt_off);
        rf_prep<<<dim3(NSEG, 16), 256, 0, stream>>>(u, uT2, cnt);
        rf_main<<<dim3(NSEG, NKC), 256, 0, stream>>>(uT2, rfs, part, cnt, out);
    } else {
        rf_pool_fallback<<<BCN / 8, 256, 0, stream>>>(u, rfs, out);
    }
}

// Round 4
// 40.887 us; speedup vs baseline: 4.4919x; 4.4919x over previous
//
#include <hip/hip_runtime.h>

#define HW    3136   // 56*56
#define KK    196
#define BCN   256    // B*C
#define KT    7      // k's per main block
#define NKC   28     // KK / KT
#define NSEG  49     // hw segments of 64
#define LOG2E 1.4426950408889634f

// ---- Kernel 1a: transpose+scale u[bc][hw] -> uT2[hw/2][bc] (hw even/odd pairs), *log2e
__global__ __launch_bounds__(256) void rf_prep(const float* __restrict__ u,
                                               float2* __restrict__ uT2) {
    __shared__ float tile[16][65];
    const int t  = threadIdx.x;
    const int h0 = blockIdx.x * 64;   // 49 hw tiles
    const int b0 = blockIdx.y * 16;   // 16 bc tiles
    const int c  = t & 63;
    const int r  = t >> 6;            // 0..3
    #pragma unroll
    for (int j = 0; j < 4; ++j)
        tile[r + 4*j][c] = u[(b0 + r + 4*j) * HW + h0 + c] * LOG2E;
    __syncthreads();
    const int tw  = t & 15;           // bc within tile
    const int hp0 = t >> 4;           // 0..15
    #pragma unroll
    for (int i = 0; i < 2; ++i) {
        const int hp = hp0 + 16 * i;  // 0..31
        float2 v;
        v.x = tile[tw][2*hp];
        v.y = tile[tw][2*hp + 1];
        uT2[(size_t)(h0/2 + hp) * BCN + b0 + tw] = v;
    }
}

// ---- Kernel 1b: repack rfs[hw][k] -> rfsT[kc][hw][KT] (contiguous per-block k-tile).
__global__ __launch_bounds__(256) void rf_repack(const float* __restrict__ rfs,
                                                 float* __restrict__ rfsT) {
    const int idx = blockIdx.x * 256 + threadIdx.x;   // kc*HW + hw
    if (idx < NKC * HW) {
        const int kc = idx / HW;
        const int hw = idx % HW;
        const float* s = rfs + (size_t)hw * KK + kc * KT;
        float* d = rfsT + (size_t)idx * KT;
        #pragma unroll
        for (int j = 0; j < KT; ++j) d[j] = s[j];
    }
}

// ---- Kernel 2: main. grid (49 seg, 28 kc), block 256 (lane = bc). No fences, no atomics.
__global__ __launch_bounds__(256) void rf_main(const float2* __restrict__ uT2,
                                               const float* __restrict__ rfsT,
                                               float* __restrict__ part) {
    const int seg = blockIdx.x;            // 0..48
    const int kc  = blockIdx.y;            // 0..27
    const int t   = threadIdx.x;           // bc
    const int h0  = seg * 64;

    float acc[KT][2];
    #pragma unroll
    for (int j = 0; j < KT; ++j) { acc[j][0] = 0.f; acc[j][1] = 0.f; }

    const float2* up = uT2 + (size_t)(h0/2) * BCN + t;
    const float*  rp = rfsT + ((size_t)kc * HW + h0) * KT;   // wave-uniform, contiguous
    #pragma unroll 8
    for (int hp = 0; hp < 32; ++hp) {
        const float2 uv = up[(size_t)hp * BCN];
        #pragma unroll
        for (int j = 0; j < KT; ++j) {
            const float r0 = rp[(2*hp)     * KT + j];
            const float r1 = rp[(2*hp + 1) * KT + j];
            acc[j][0] += __builtin_amdgcn_exp2f(uv.x * r0);
            acc[j][1] += __builtin_amdgcn_exp2f(uv.y * r1);
        }
    }

    float* pp = part + (size_t)(kc * NSEG + seg) * KT * BCN + t;
    #pragma unroll
    for (int j = 0; j < KT; ++j)
        pp[j * BCN] = acc[j][0] + acc[j][1];
}

// ---- Kernel 3: reduce 49 segments (fully unrolled, 49 independent loads), p = S/(1+S).
__global__ __launch_bounds__(256) void rf_fin(const float* __restrict__ part,
                                              float* __restrict__ out) {
    const int k = blockIdx.x;    // 0..195
    const int t = threadIdx.x;   // bc
    const int kc = k / KT;
    const int j  = k % KT;
    const float* pb = part + ((size_t)kc * NSEG * KT + j) * BCN + t;
    float s = 0.f;
    #pragma unroll
    for (int sg = 0; sg < NSEG; ++sg)
        s += pb[(size_t)sg * KT * BCN];
    out[(size_t)t * KK + k] = s / (1.0f + s);
}

// ---- Fallback (no workspace): monolithic, lane = k. Known-correct path.
__global__ __launch_bounds__(256) void rf_pool_fallback(const float* __restrict__ u,
                                                        const float* __restrict__ rfs,
                                                        float* __restrict__ out) {
    const int grp = blockIdx.x;
    const int tid = threadIdx.x;
    const int bc0 = grp * 8;
    __shared__ __align__(16) float u_lds[8][196];
    float sum[8];
    #pragma unroll
    for (int g = 0; g < 8; ++g) sum[g] = 0.0f;
    for (int base = 0; base < HW; base += 196) {
        __syncthreads();
        if (tid < 196) {
            #pragma unroll
            for (int g = 0; g < 8; ++g)
                u_lds[g][tid] = u[(bc0 + g) * HW + base + tid] * LOG2E;
        }
        __syncthreads();
        if (tid < KK) {
            const float* rp = rfs + (size_t)base * KK + tid;
            for (int h = 0; h < 196; h += 4) {
                float rf0 = rp[(h + 0) * KK];
                float rf1 = rp[(h + 1) * KK];
                float rf2 = rp[(h + 2) * KK];
                float rf3 = rp[(h + 3) * KK];
                #pragma unroll
                for (int g = 0; g < 8; ++g) {
                    float4 ug = *(const float4*)&u_lds[g][h];
                    sum[g] += __builtin_amdgcn_exp2f(ug.x * rf0);
                    sum[g] += __builtin_amdgcn_exp2f(ug.y * rf1);
                    sum[g] += __builtin_amdgcn_exp2f(ug.z * rf2);
                    sum[g] += __builtin_amdgcn_exp2f(ug.w * rf3);
                }
            }
        }
    }
    if (tid < KK) {
        #pragma unroll
        for (int g = 0; g < 8; ++g) {
            float s = sum[g];
            out[(bc0 + g) * HW / HW * KK + tid] = s / (s + 1.0f); // = (bc0+g)*KK + tid
        }
    }
}

extern "C" void kernel_launch(void* const* d_in, const int* in_sizes, int n_in,
                              void* d_out, int out_size, void* d_ws, size_t ws_size,
                              hipStream_t stream) {
    const float* u   = (const float*)d_in[0];   // (8,32,56,56) f32
    const float* rfs = (const float*)d_in[1];   // (56,56,196) f32
    float* out = (float*)d_out;                 // (8,32,196) f32

    const size_t uT2_off  = 0;                       // 3.2 MB
    const size_t rfsT_off = 4u << 20;                // @4 MB, 2.46 MB
    const size_t part_off = 8u << 20;                // @8 MB, 9.84 MB
    const size_t need     = part_off + (size_t)NKC * NSEG * KT * BCN * sizeof(float);
    if (ws_size >= need) {
        float2* uT2  = (float2*)((char*)d_ws + uT2_off);
        float*  rfsT = (float*)((char*)d_ws + rfsT_off);
        float*  part = (float*)((char*)d_ws + part_off);
        rf_prep<<<dim3(NSEG, 16), 256, 0, stream>>>(u, uT2);
        rf_repack<<<(NKC * HW + 255) / 256, 256, 0, stream>>>(rfs, rfsT);
        rf_main<<<dim3(NSEG, NKC), 256, 0, stream>>>(uT2, rfsT, part);
        rf_fin<<<KK, 256, 0, stream>>>(part, out);
    } else {
        rf_pool_fallback<<<BCN / 8, 256, 0, stream>>>(u, rfs, out);
    }
}

// Round 5
// 28.734 us; speedup vs baseline: 6.3917x; 1.4229x over previous
//
#include <hip/hip_runtime.h>

#define HW    3136   // 56*56
#define KK    196
#define BCN   256    // B*C
#define KT    7      // k's per main block
#define NKC   28     // KK / KT
#define NSEG  49     // hw segments of 64
#define LOG2E 1.4426950408889634f
// u prescale: log2(e) * 2^23 (Schraudolph domain)
#define PRESCALE (1.4426950408889634f * 8388608.0f)
// centered Schraudolph bias: 127*2^23 - 299487  (max rel err ~ +/-3.6%)
#define SCH_BIAS 1065053729.0f

// ---- Kernel 1: fused prep. Blocks [0,784): transpose+prescale u -> uT2[hw/2][bc].
//                Blocks [784,1127): repack rfs[hw][k] -> rfsT[kc][hw][KT].
__global__ __launch_bounds__(256) void rf_prep(const float* __restrict__ u,
                                               const float* __restrict__ rfs,
                                               float2* __restrict__ uT2,
                                               float* __restrict__ rfsT) {
    const int b = blockIdx.x;
    const int t = threadIdx.x;
    if (b < 784) {
        __shared__ float tile[16][65];
        const int h0 = (b % 49) * 64;     // hw tile
        const int b0 = (b / 49) * 16;     // bc tile
        const int c  = t & 63;
        const int r  = t >> 6;            // 0..3
        #pragma unroll
        for (int j = 0; j < 4; ++j)
            tile[r + 4*j][c] = u[(b0 + r + 4*j) * HW + h0 + c] * PRESCALE;
        __syncthreads();
        const int tw  = t & 15;           // bc within tile
        const int hp0 = t >> 4;           // 0..15
        #pragma unroll
        for (int i = 0; i < 2; ++i) {
            const int hp = hp0 + 16 * i;  // 0..31
            float2 v;
            v.x = tile[tw][2*hp];
            v.y = tile[tw][2*hp + 1];
            uT2[(size_t)(h0/2 + hp) * BCN + b0 + tw] = v;
        }
    } else {
        const int idx = (b - 784) * 256 + t;   // kc*HW + hw  (28*3136 = 343*256 exact)
        if (idx < NKC * HW) {
            const int kc = idx / HW;
            const int hw = idx % HW;
            const float* s = rfs + (size_t)hw * KK + kc * KT;
            float* d = rfsT + (size_t)idx * KT;
            #pragma unroll
            for (int j = 0; j < KT; ++j) d[j] = s[j];
        }
    }
}

// ---- Kernel 2: main. grid (49 seg, 28 kc), block 256 (lane = bc).
// Schraudolph exp2: acc += bitcast<float>((int)(u''*r + BIAS)) — 3 full-rate VALU ops/elem.
__global__ __launch_bounds__(256) void rf_main(const float2* __restrict__ uT2,
                                               const float* __restrict__ rfsT,
                                               float* __restrict__ part) {
    const int seg = blockIdx.x;            // 0..48
    const int kc  = blockIdx.y;            // 0..27
    const int t   = threadIdx.x;           // bc
    const int h0  = seg * 64;

    float acc[KT][2];
    #pragma unroll
    for (int j = 0; j < KT; ++j) { acc[j][0] = 0.f; acc[j][1] = 0.f; }

    const float2* up = uT2 + (size_t)(h0/2) * BCN + t;
    const float*  rp = rfsT + ((size_t)kc * HW + h0) * KT;   // wave-uniform, contiguous
    #pragma unroll 4
    for (int hp = 0; hp < 32; ++hp) {
        const float2 uv = up[(size_t)hp * BCN];
        #pragma unroll
        for (int j = 0; j < KT; ++j) {
            const float r0 = rp[(2*hp)     * KT + j];
            const float r1 = rp[(2*hp + 1) * KT + j];
            acc[j][0] += __int_as_float((int)fmaf(uv.x, r0, SCH_BIAS));
            acc[j][1] += __int_as_float((int)fmaf(uv.y, r1, SCH_BIAS));
        }
    }

    float* pp = part + (size_t)(kc * NSEG + seg) * KT * BCN + t;
    #pragma unroll
    for (int j = 0; j < KT; ++j)
        pp[j * BCN] = acc[j][0] + acc[j][1];
}

// ---- Kernel 3: reduce 49 segments, p = S/(1+S).
__global__ __launch_bounds__(256) void rf_fin(const float* __restrict__ part,
                                              float* __restrict__ out) {
    const int k = blockIdx.x;    // 0..195
    const int t = threadIdx.x;   // bc
    const int kc = k / KT;
    const int j  = k % KT;
    const float* pb = part + ((size_t)kc * NSEG * KT + j) * BCN + t;
    float s = 0.f;
    #pragma unroll
    for (int sg = 0; sg < NSEG; ++sg)
        s += pb[(size_t)sg * KT * BCN];
    out[(size_t)t * KK + k] = s / (1.0f + s);
}

// ---- Fallback (no workspace): monolithic, lane = k. Known-correct path (real exp2).
__global__ __launch_bounds__(256) void rf_pool_fallback(const float* __restrict__ u,
                                                        const float* __restrict__ rfs,
                                                        float* __restrict__ out) {
    const int grp = blockIdx.x;
    const int tid = threadIdx.x;
    const int bc0 = grp * 8;
    __shared__ __align__(16) float u_lds[8][196];
    float sum[8];
    #pragma unroll
    for (int g = 0; g < 8; ++g) sum[g] = 0.0f;
    for (int base = 0; base < HW; base += 196) {
        __syncthreads();
        if (tid < 196) {
            #pragma unroll
            for (int g = 0; g < 8; ++g)
                u_lds[g][tid] = u[(bc0 + g) * HW + base + tid] * LOG2E;
        }
        __syncthreads();
        if (tid < KK) {
            const float* rp = rfs + (size_t)base * KK + tid;
            for (int h = 0; h < 196; h += 4) {
                float rf0 = rp[(h + 0) * KK];
                float rf1 = rp[(h + 1) * KK];
                float rf2 = rp[(h + 2) * KK];
                float rf3 = rp[(h + 3) * KK];
                #pragma unroll
                for (int g = 0; g < 8; ++g) {
                    float4 ug = *(const float4*)&u_lds[g][h];
                    sum[g] += __builtin_amdgcn_exp2f(ug.x * rf0);
                    sum[g] += __builtin_amdgcn_exp2f(ug.y * rf1);
                    sum[g] += __builtin_amdgcn_exp2f(ug.z * rf2);
                    sum[g] += __builtin_amdgcn_exp2f(ug.w * rf3);
                }
            }
        }
    }
    if (tid < KK) {
        #pragma unroll
        for (int g = 0; g < 8; ++g) {
            float s = sum[g];
            out[(size_t)(bc0 + g) * KK + tid] = s / (s + 1.0f);
        }
    }
}

extern "C" void kernel_launch(void* const* d_in, const int* in_sizes, int n_in,
                              void* d_out, int out_size, void* d_ws, size_t ws_size,
                              hipStream_t stream) {
    const float* u   = (const float*)d_in[0];   // (8,32,56,56) f32
    const float* rfs = (const float*)d_in[1];   // (56,56,196) f32
    float* out = (float*)d_out;                 // (8,32,196) f32

    const size_t uT2_off  = 0;                       // 3.2 MB
    const size_t rfsT_off = 4u << 20;                // @4 MB, 2.46 MB
    const size_t part_off = 8u << 20;                // @8 MB, 9.84 MB
    const size_t need     = part_off + (size_t)NKC * NSEG * KT * BCN * sizeof(float);
    if (ws_size >= need) {
        float2* uT2  = (float2*)((char*)d_ws + uT2_off);
        float*  rfsT = (float*)((char*)d_ws + rfsT_off);
        float*  part = (float*)((char*)d_ws + part_off);
        rf_prep<<<784 + 343, 256, 0, stream>>>(u, rfs, uT2, rfsT);
        rf_main<<<dim3(NSEG, NKC), 256, 0, stream>>>(uT2, rfsT, part);
        rf_fin<<<KK, 256, 0, stream>>>(part, out);
    } else {
        rf_pool_fallback<<<BCN / 8, 256, 0, stream>>>(u, rfs, out);
    }
}